// Round 5
// baseline (279.051 us; speedup 1.0000x reference)
//
#include <hip/hip_runtime.h>

// WassersteinLoss: per-row W1 = (1/N) * sum_i |sort(u)[i] - sort(v)[i]|, mean over rows.
// R9: negated-space compare-exchange.
//   R8 post-mortem: T ~= T_VALU(116us) + T_DS(33us). ce2 costs 3 VALU + 1 SALU
//   s_xor_b64 PER ELEMENT (1728/thread, scalar unit shared per CU). New scheme:
//   keep-max lanes hold sign-negated values; every cross CE collapses to
//   x' = fminf(x', -o') (one VALU; neg is a free src modifier). mov_dpp feeding
//   a single-use fminf is the exact GCNDPPCombine pattern -> v_min_f32_dpp
//   (1 inst exchange+select). Side-bit transitions = 1 sign-xor/elem with
//   per-thread precomputed masks. bperm passes: 2 VALU -> 1 VALU (+1 DS, same).
//   Cross VALU 4608 -> 3904(fused)..5056(unfused); SALU -1728 either way.
//   Tie safety: inputs >= 0; +/-0 cases checked lane-wise -> bit-exact.
// Carried: blocked layout, mirror bitonic, DPP m=1,2,8 + mirrors X=1,3,7,15,
//   bperm m=4,16,32 + mirrors X=31,63, wave-role-split t^127 LDS stage (17 KB),
//   launch_bounds(256,4) (spill tripwire: WRITE_SIZE must stay ~64 KB).

constexpr int N_ELEM  = 4096;
constexpr int V       = 32;     // elements per thread per array
constexpr int THREADS = 256;    // 4 waves = 2 rows per block

// ---- in-register ascending merge of S-blocks: mirror + descend S/4..1 ----
template<int S>
__device__ __forceinline__ void reg_merge(float r[V]) {
    #pragma unroll
    for (int k = 0; k < V; ++k) {
        if ((k & (S >> 1)) == 0) {
            const int j = k ^ (S - 1);
            const float a = r[k], b = r[j];
            r[k] = fminf(a, b);
            r[j] = fmaxf(a, b);
        }
    }
    #pragma unroll
    for (int s = S >> 2; s >= 1; s >>= 1) {
        #pragma unroll
        for (int k = 0; k < V; ++k) {
            if ((k & s) == 0) {
                const float a = r[k], b = r[k + s];
                r[k]     = fminf(a, b);
                r[k + s] = fmaxf(a, b);
            }
        }
    }
}

// ---- ascending register descend, strides 16..1 (tail of every cross stage) ----
__device__ __forceinline__ void reg_tail_asc(float r[V]) {
    #pragma unroll
    for (int s = 16; s >= 1; s >>= 1) {
        #pragma unroll
        for (int k = 0; k < V; ++k) {
            if ((k & s) == 0) {
                const float a = r[k], b = r[k + s];
                r[k]     = fminf(a, b);
                r[k + s] = fmaxf(a, b);
            }
        }
    }
}
__device__ __forceinline__ void tail2(float ru[V], float rv[V]) {
    reg_tail_asc(ru);
    reg_tail_asc(rv);
}

template<int CTRL>
__device__ __forceinline__ float dpp_x(float x) {
    return __int_as_float(__builtin_amdgcn_mov_dpp(__float_as_int(x), CTRL, 0xF, 0xF, true));
}
__device__ __forceinline__ float bperm_x(int pa, float x) {
    return __int_as_float(__builtin_amdgcn_ds_bpermute(pa, __float_as_int(x)));
}

// ---- sign-state transition: xor all elements with per-lane mask m ----
__device__ __forceinline__ void trans(float r[V], unsigned m) {
    #pragma unroll
    for (int k = 0; k < V; ++k)
        r[k] = __int_as_float(__float_as_int(r[k]) ^ m);
}
__device__ __forceinline__ void trans2(float ru[V], float rv[V], unsigned m) {
    trans(ru, m);
    trans(rv, m);
}

// ---- negated-space cross passes: x' = min(x', -exchange(x')) ----
// DPP xor pass (partner lane^m encoded in CTRL). Single-use dpp -> v_min_f32_dpp.
template<int CTRL>
__device__ __forceinline__ void dppmin_pass(float ru[V], float rv[V]) {
    #pragma unroll
    for (int k = 0; k < V; ++k) {
        ru[k] = fminf(ru[k], -dpp_x<CTRL>(ru[k]));
        rv[k] = fminf(rv[k], -dpp_x<CTRL>(rv[k]));
    }
}
__device__ __forceinline__ void bpermmin_pass(float ru[V], float rv[V], int pa) {
    #pragma unroll
    for (int k = 0; k < V; ++k) {
        ru[k] = fminf(ru[k], -bperm_x(pa, ru[k]));
        rv[k] = fminf(rv[k], -bperm_x(pa, rv[k]));
    }
}
// Mirror passes: partner (lane^X, 31-k). Pairs (k,31-k) jointly: reads before writes.
template<int CTRL>
__device__ __forceinline__ void dppmin_mirror(float ru[V], float rv[V]) {
    #pragma unroll
    for (int k = 0; k < V / 2; ++k) {
        const int j = V - 1 - k;
        const float ua = dpp_x<CTRL>(ru[j]);
        const float ub = dpp_x<CTRL>(ru[k]);
        ru[k] = fminf(ru[k], -ua);
        ru[j] = fminf(ru[j], -ub);
        const float va = dpp_x<CTRL>(rv[j]);
        const float vb = dpp_x<CTRL>(rv[k]);
        rv[k] = fminf(rv[k], -va);
        rv[j] = fminf(rv[j], -vb);
    }
}
__device__ __forceinline__ void bpermmin_mirror(float ru[V], float rv[V], int pa) {
    #pragma unroll
    for (int k = 0; k < V / 2; ++k) {
        const int j = V - 1 - k;
        const float ua = bperm_x(pa, ru[j]);
        const float ub = bperm_x(pa, ru[k]);
        ru[k] = fminf(ru[k], -ua);
        ru[j] = fminf(ru[j], -ub);
        const float va = bperm_x(pa, rv[j]);
        const float vb = bperm_x(pa, rv[k]);
        rv[k] = fminf(rv[k], -va);
        rv[j] = fminf(rv[j], -vb);
    }
}

// Per-thread sign masks / bperm addresses (computed once, live in VGPRs).
struct NegCtx {
    unsigned s1, s2, s4, s8, s16, s32;        // enter/exit masks per side bit
    unsigned d21, d42, d84, d168, d3216;      // deltas between adjacent side bits
    int pa4, pa16, pa32, pm31, pm63;          // bperm byte addresses
};

__global__ __launch_bounds__(THREADS, 4) void w1_rows_kernel(
    const float* __restrict__ pred,
    const float* __restrict__ tru,
    float* __restrict__ out,
    float scale)
{
    // Staging for UPPER threads only (t&64): 128 slots x stride 33 = 16896 B.
    __shared__ float xbuf[128 * 33];
    __shared__ float wsum[THREADS / 64];

    const int tid  = threadIdx.x;
    const int t    = tid & 127;            // thread index within the row (0..127)
    const int lane = tid & 63;
    const int row  = blockIdx.x * 2 + (tid >> 7);
    const size_t base = (size_t)row * N_ELEM + (size_t)t * V;

    // Blocked layout: row-thread t owns global indices [32t, 32t+32).
    float ru[V], rv[V];
    {
        const float4* u4 = (const float4*)(pred + base);
        const float4* v4 = (const float4*)(tru  + base);
        #pragma unroll
        for (int c = 0; c < V / 4; ++c) {
            float4 a = u4[c], b = v4[c];
            ru[4*c+0] = a.x; ru[4*c+1] = a.y; ru[4*c+2] = a.z; ru[4*c+3] = a.w;
            rv[4*c+0] = b.x; rv[4*c+1] = b.y; rv[4*c+2] = b.z; rv[4*c+3] = b.w;
        }
    }

    NegCtx M;
    M.s1  = (lane & 1)  ? 0x80000000u : 0u;
    M.s2  = (lane & 2)  ? 0x80000000u : 0u;
    M.s4  = (lane & 4)  ? 0x80000000u : 0u;
    M.s8  = (lane & 8)  ? 0x80000000u : 0u;
    M.s16 = (lane & 16) ? 0x80000000u : 0u;
    M.s32 = (lane & 32) ? 0x80000000u : 0u;
    M.d21   = M.s2  ^ M.s1;
    M.d42   = M.s4  ^ M.s2;
    M.d84   = M.s8  ^ M.s4;
    M.d168  = M.s16 ^ M.s8;
    M.d3216 = M.s32 ^ M.s16;
    M.pa4  = (lane ^ 4)  << 2;
    M.pa16 = (lane ^ 16) << 2;
    M.pa32 = (lane ^ 32) << 2;
    M.pm31 = (lane ^ 31) << 2;
    M.pm63 = (lane ^ 63) << 2;

    // Stages S=2..32: fully in-register ascending sort of each 32-run.
    reg_merge<2>(ru);  reg_merge<2>(rv);
    reg_merge<4>(ru);  reg_merge<4>(rv);
    reg_merge<8>(ru);  reg_merge<8>(rv);
    reg_merge<16>(ru); reg_merge<16>(rv);
    reg_merge<32>(ru); reg_merge<32>(rv);

    // Stage S=64: mirror X=1 (side bit 1).
    trans2(ru, rv, M.s1);
    dppmin_mirror<0xB1>(ru, rv);
    trans2(ru, rv, M.s1);
    tail2(ru, rv);

    // Stage S=128: mirror X=3 (b=2); descend m=1.
    trans2(ru, rv, M.s2);
    dppmin_mirror<0x1B>(ru, rv);
    trans2(ru, rv, M.d21);
    dppmin_pass<0xB1>(ru, rv);
    trans2(ru, rv, M.s1);
    tail2(ru, rv);

    // Stage S=256: mirror X=7 (b=4); descend m=2,1.
    trans2(ru, rv, M.s4);
    dppmin_mirror<0x141>(ru, rv);
    trans2(ru, rv, M.d42);
    dppmin_pass<0x4E>(ru, rv);
    trans2(ru, rv, M.d21);
    dppmin_pass<0xB1>(ru, rv);
    trans2(ru, rv, M.s1);
    tail2(ru, rv);

    // Stage S=512: mirror X=15 (b=8); descend m=4,2,1.
    trans2(ru, rv, M.s8);
    dppmin_mirror<0x140>(ru, rv);
    trans2(ru, rv, M.d84);
    bpermmin_pass(ru, rv, M.pa4);
    trans2(ru, rv, M.d42);
    dppmin_pass<0x4E>(ru, rv);
    trans2(ru, rv, M.d21);
    dppmin_pass<0xB1>(ru, rv);
    trans2(ru, rv, M.s1);
    tail2(ru, rv);

    // Stage S=1024: mirror X=31 (b=16, bperm); descend m=8,4,2,1.
    trans2(ru, rv, M.s16);
    bpermmin_mirror(ru, rv, M.pm31);
    trans2(ru, rv, M.d168);
    dppmin_pass<0x128>(ru, rv);
    trans2(ru, rv, M.d84);
    bpermmin_pass(ru, rv, M.pa4);
    trans2(ru, rv, M.d42);
    dppmin_pass<0x4E>(ru, rv);
    trans2(ru, rv, M.d21);
    dppmin_pass<0xB1>(ru, rv);
    trans2(ru, rv, M.s1);
    tail2(ru, rv);

    // Stage S=2048: mirror X=63 (b=32, bperm); descend m=16,8,4,2,1.
    trans2(ru, rv, M.s32);
    bpermmin_mirror(ru, rv, M.pm63);
    trans2(ru, rv, M.d3216);
    bpermmin_pass(ru, rv, M.pa16);
    trans2(ru, rv, M.d168);
    dppmin_pass<0x128>(ru, rv);
    trans2(ru, rv, M.d84);
    bpermmin_pass(ru, rv, M.pa4);
    trans2(ru, rv, M.d42);
    dppmin_pass<0x4E>(ru, rv);
    trans2(ru, rv, M.d21);
    dppmin_pass<0xB1>(ru, rv);
    trans2(ru, rv, M.s1);
    tail2(ru, rv);

    // Stage S=4096: mirror pass g <-> g^4095, i.e. (t,k) <-> (t^127, 31-k).
    // Wave-role split (TRUE space): uppers (t&64) stage all 32 regs; lowers read
    // partner reversed, keep min, write max back; uppers re-read.
    {
        const bool is_upper = (t & 64) != 0;
        const int  slot_row = (tid >> 7) * 64;
        const int  my_base  = (slot_row + lane) * 33;        // uppers' own slot
        const int  pa_base  = (slot_row + (63 - lane)) * 33; // lowers' partner slot

        // ---- array u ----
        if (is_upper) {
            #pragma unroll
            for (int k = 0; k < V; ++k) xbuf[my_base + k] = ru[k];
        }
        __syncthreads();
        if (!is_upper) {
            #pragma unroll
            for (int k = 0; k < V; ++k) {
                const int  e = V - 1 - k;
                const float o  = xbuf[pa_base + e];
                const float mx = fmaxf(ru[k], o);
                ru[k] = fminf(ru[k], o);          // lower keeps min
                xbuf[pa_base + e] = mx;           // partner's result
            }
        }
        __syncthreads();
        if (is_upper) {
            #pragma unroll
            for (int k = 0; k < V; ++k) ru[k] = xbuf[my_base + k];
        }

        // ---- array v ---- (uppers' own-slot read->write is program-ordered)
        if (is_upper) {
            #pragma unroll
            for (int k = 0; k < V; ++k) xbuf[my_base + k] = rv[k];
        }
        __syncthreads();
        if (!is_upper) {
            #pragma unroll
            for (int k = 0; k < V; ++k) {
                const int  e = V - 1 - k;
                const float o  = xbuf[pa_base + e];
                const float mx = fmaxf(rv[k], o);
                rv[k] = fminf(rv[k], o);
                xbuf[pa_base + e] = mx;
            }
        }
        __syncthreads();
        if (is_upper) {
            #pragma unroll
            for (int k = 0; k < V; ++k) rv[k] = xbuf[my_base + k];
        }

        // Descend m=32..1 in negated space, then register tail.
        trans2(ru, rv, M.s32);
        bpermmin_pass(ru, rv, M.pa32);
        trans2(ru, rv, M.d3216);
        bpermmin_pass(ru, rv, M.pa16);
        trans2(ru, rv, M.d168);
        dppmin_pass<0x128>(ru, rv);
        trans2(ru, rv, M.d84);
        bpermmin_pass(ru, rv, M.pa4);
        trans2(ru, rv, M.d42);
        dppmin_pass<0x4E>(ru, rv);
        trans2(ru, rv, M.d21);
        dppmin_pass<0xB1>(ru, rv);
        trans2(ru, rv, M.s1);
        tail2(ru, rv);
    }

    // Epilogue: per-thread |diff| sum, wave reduce, block reduce, one atomic.
    float part = 0.f;
    #pragma unroll
    for (int k = 0; k < V; ++k) part += fabsf(ru[k] - rv[k]);

    #pragma unroll
    for (int off = 32; off > 0; off >>= 1)
        part += __shfl_down(part, off, 64);

    const int wid = tid >> 6;
    if (lane == 0) wsum[wid] = part;
    __syncthreads();
    if (tid == 0) {
        float tot = wsum[0] + wsum[1] + wsum[2] + wsum[3];
        atomicAdd(out, tot * scale);
    }
}

extern "C" void kernel_launch(void* const* d_in, const int* in_sizes, int n_in,
                              void* d_out, int out_size, void* d_ws, size_t ws_size,
                              hipStream_t stream)
{
    (void)n_in; (void)out_size; (void)d_ws; (void)ws_size;

    const float* pred = (const float*)d_in[0];
    const float* tru  = (const float*)d_in[1];
    float* out = (float*)d_out;

    const int B = in_sizes[0] / N_ELEM;   // 4096 rows

    hipMemsetAsync(out, 0, sizeof(float), stream);

    const float scale = 1.0f / ((float)N_ELEM * (float)B);
    w1_rows_kernel<<<B / 2, THREADS, 0, stream>>>(pred, tru, out, scale);
}

// Round 9
// 251.009 us; speedup vs baseline: 1.1117x; 1.1117x over previous
//
#include <hip/hip_runtime.h>

// WassersteinLoss: per-row W1 = (1/N) * sum_i |sort(u)[i] - sort(v)[i]|, mean over rows.
// R13: doubly-robust permlane CE. R12 post-mortem: R12 == R8 + asm-permlane only
//   and FAILED -> the asm permlane swap is the broken piece, conclusively.
//   Root cause candidate: "swap" vs "full-exchange-with-rowswap" semantics; under
//   the latter, a=b=x yields {partner, partner} and min(a,b) = partner (own value
//   silently dropped). Fixes:
//   1) CE includes own value: x = keep_min ? min3(x,r0,r1) : max3(x,r0,r1)
//      (v_min3/v_max3_f32) — correct whether {r0,r1} = {own,partner} or
//      {partner,partner}. Same cost, 0 DS.
//   2) Use __builtin_amdgcn_permlane{16,32}_swap (compiler-modeled dataflow,
//      verified to exist on gfx950 per learn_hip m255/T12) instead of inline asm,
//      guarded by __has_builtin; fallback = R8-proven bperm (worst case: R8 perf,
//      absmax 0).
//   Single delta vs R8 (m=4 stays bperm; ror experiment queued behind this).
//   Gate: absmax != 0 -> permlane abandoned, full R8 revert + pivot.
// Carried from R8: blocked layout, ascending mirror bitonic, 2-VALU ce2,
//   DPP m=1,2,8 + mirrors X=1,3,7,15, bperm m=4 + mirrors X=31,63,
//   wave-role-split LDS t^127 stage (17 KB, 0 conflicts), launch_bounds(256,4)
//   (tripwire: WRITE_SIZE must stay ~64 KB).

constexpr int N_ELEM  = 4096;
constexpr int V       = 32;     // elements per thread per array
constexpr int THREADS = 256;    // 4 waves = 2 rows per block

#if __has_builtin(__builtin_amdgcn_permlane16_swap) && __has_builtin(__builtin_amdgcn_permlane32_swap)
#define HAVE_PLSWAP 1
typedef unsigned uv2 __attribute__((ext_vector_type(2)));
#else
#define HAVE_PLSWAP 0
#endif

// ---- compare-select: keep min(x,o) if keep_min, else max(x,o). ----
__device__ __forceinline__ float ce2(float x, float o, bool keep_min) {
    return ((o < x) != keep_min) ? x : o;
}

// ---- in-register ascending merge of S-blocks: mirror + descend S/4..1 ----
template<int S>
__device__ __forceinline__ void reg_merge(float r[V]) {
    #pragma unroll
    for (int k = 0; k < V; ++k) {
        if ((k & (S >> 1)) == 0) {
            const int j = k ^ (S - 1);          // complement low bits = mirror partner
            const float a = r[k], b = r[j];
            r[k] = fminf(a, b);
            r[j] = fmaxf(a, b);
        }
    }
    #pragma unroll
    for (int s = S >> 2; s >= 1; s >>= 1) {
        #pragma unroll
        for (int k = 0; k < V; ++k) {
            if ((k & s) == 0) {
                const float a = r[k], b = r[k + s];
                r[k]     = fminf(a, b);
                r[k + s] = fmaxf(a, b);
            }
        }
    }
}

// ---- ascending register descend, strides 16..1 (tail of every cross stage) ----
__device__ __forceinline__ void reg_tail_asc(float r[V]) {
    #pragma unroll
    for (int s = 16; s >= 1; s >>= 1) {
        #pragma unroll
        for (int k = 0; k < V; ++k) {
            if ((k & s) == 0) {
                const float a = r[k], b = r[k + s];
                r[k]     = fminf(a, b);
                r[k + s] = fmaxf(a, b);
            }
        }
    }
}

template<int CTRL>
__device__ __forceinline__ float dpp_x(float x) {
    return __int_as_float(__builtin_amdgcn_mov_dpp(__float_as_int(x), CTRL, 0xF, 0xF, true));
}
__device__ __forceinline__ float bperm_x(int pa, float x) {
    return __int_as_float(__builtin_amdgcn_ds_bpermute(pa, __float_as_int(x)));
}

#if HAVE_PLSWAP
// Doubly-robust permlane CE: r = swap(x, x) gives {r0,r1} = {own,partner} OR
// {partner,partner} depending on the HW's row-motion semantics; including x in
// the reduction makes the CE correct under either. Fuses to v_min3/v_max3.
__device__ __forceinline__ float pl16_ce(float x, bool keep_min) {
    const unsigned xu = __float_as_uint(x);
    const uv2 r = __builtin_amdgcn_permlane16_swap(xu, xu, false, false);
    const float a = __uint_as_float(r[0]);
    const float b = __uint_as_float(r[1]);
    return keep_min ? fminf(fminf(x, a), b) : fmaxf(fmaxf(x, a), b);
}
__device__ __forceinline__ float pl32_ce(float x, bool keep_min) {
    const unsigned xu = __float_as_uint(x);
    const uv2 r = __builtin_amdgcn_permlane32_swap(xu, xu, false, false);
    const float a = __uint_as_float(r[0]);
    const float b = __uint_as_float(r[1]);
    return keep_min ? fminf(fminf(x, a), b) : fmaxf(fmaxf(x, a), b);
}
#endif

// ---- descend xor pass, lane partner lane^M, keep_min at (lane&M)==0 ----
template<int M>
__device__ __forceinline__ void xor_pass(float ru[V], float rv[V], int lane) {
    const bool keep_min = (lane & M) == 0;
    if constexpr (M == 1 || M == 2 || M == 8) {
        constexpr int ctrl = (M == 1) ? 0xB1 : (M == 2) ? 0x4E : 0x128;
        #pragma unroll
        for (int k = 0; k < V; ++k) {
            ru[k] = ce2(ru[k], dpp_x<ctrl>(ru[k]), keep_min);
            rv[k] = ce2(rv[k], dpp_x<ctrl>(rv[k]), keep_min);
        }
    } else if constexpr (M == 4) {
        // R8-proven bperm path.
        const int pa = (lane ^ 4) << 2;
        #pragma unroll
        for (int k = 0; k < V; ++k) {
            ru[k] = ce2(ru[k], bperm_x(pa, ru[k]), keep_min);
            rv[k] = ce2(rv[k], bperm_x(pa, rv[k]), keep_min);
        }
    } else if constexpr (M == 16) {
#if HAVE_PLSWAP
        #pragma unroll
        for (int k = 0; k < V; ++k) {
            ru[k] = pl16_ce(ru[k], keep_min);
            rv[k] = pl16_ce(rv[k], keep_min);
        }
#else
        const int pa = (lane ^ 16) << 2;
        #pragma unroll
        for (int k = 0; k < V; ++k) {
            ru[k] = ce2(ru[k], bperm_x(pa, ru[k]), keep_min);
            rv[k] = ce2(rv[k], bperm_x(pa, rv[k]), keep_min);
        }
#endif
    } else {  // M == 32
#if HAVE_PLSWAP
        #pragma unroll
        for (int k = 0; k < V; ++k) {
            ru[k] = pl32_ce(ru[k], keep_min);
            rv[k] = pl32_ce(rv[k], keep_min);
        }
#else
        const int pa = (lane ^ 32) << 2;
        #pragma unroll
        for (int k = 0; k < V; ++k) {
            ru[k] = ce2(ru[k], bperm_x(pa, ru[k]), keep_min);
            rv[k] = ce2(rv[k], bperm_x(pa, rv[k]), keep_min);
        }
#endif
    }
}

// ---- cross descend m=MMAX..1 then register tail (strides 16..1) ----
template<int MMAX>
__device__ __forceinline__ void cross_descend(float ru[V], float rv[V], int lane) {
    if constexpr (MMAX >= 32) xor_pass<32>(ru, rv, lane);
    if constexpr (MMAX >= 16) xor_pass<16>(ru, rv, lane);
    if constexpr (MMAX >= 8)  xor_pass<8>(ru, rv, lane);
    if constexpr (MMAX >= 4)  xor_pass<4>(ru, rv, lane);
    if constexpr (MMAX >= 2)  xor_pass<2>(ru, rv, lane);
    if constexpr (MMAX >= 1)  xor_pass<1>(ru, rv, lane);
    reg_tail_asc(ru);
    reg_tail_asc(rv);
}

// DPP ctrl for mirror partner lane^X, or -1 (-> bperm).
template<int X>
static constexpr int mirror_dpp_ctrl() {
    return X == 1 ? 0xB1 : X == 3 ? 0x1B : X == 7 ? 0x141 : X == 15 ? 0x140 : -1;
}

// ---- cross mirror pass: (t,k) <-> (t^X, 31-k); keep_min at (t & (X+1)/2)==0.
//      Pairs (k, 31-k) handled jointly so reads precede writes (no hazard). ----
template<int X>
__device__ __forceinline__ void mirror_pass(float ru[V], float rv[V], int lane) {
    const bool keep_min = (lane & ((X + 1) >> 1)) == 0;
    constexpr int ctrl = mirror_dpp_ctrl<X>();
    if constexpr (ctrl != -1) {
        #pragma unroll
        for (int k = 0; k < V / 2; ++k) {
            const int j = V - 1 - k;
            const float ua = dpp_x<ctrl>(ru[j]);
            const float ub = dpp_x<ctrl>(ru[k]);
            ru[k] = ce2(ru[k], ua, keep_min);
            ru[j] = ce2(ru[j], ub, keep_min);
            const float va = dpp_x<ctrl>(rv[j]);
            const float vb = dpp_x<ctrl>(rv[k]);
            rv[k] = ce2(rv[k], va, keep_min);
            rv[j] = ce2(rv[j], vb, keep_min);
        }
    } else {
        const int pa = (lane ^ X) << 2;
        #pragma unroll
        for (int k = 0; k < V / 2; ++k) {
            const int j = V - 1 - k;
            const float ua = bperm_x(pa, ru[j]);
            const float ub = bperm_x(pa, ru[k]);
            ru[k] = ce2(ru[k], ua, keep_min);
            ru[j] = ce2(ru[j], ub, keep_min);
            const float va = bperm_x(pa, rv[j]);
            const float vb = bperm_x(pa, rv[k]);
            rv[k] = ce2(rv[k], va, keep_min);
            rv[j] = ce2(rv[j], vb, keep_min);
        }
    }
}

// ---- full merge stage S (64..2048): cross mirror + cross descend + reg tail ----
template<int S>
__device__ __forceinline__ void stage_m(float ru[V], float rv[V], int lane) {
    mirror_pass<(S >> 5) - 1>(ru, rv, lane);   // X = S/32 - 1  (t-bit mirror mask)
    cross_descend<(S >> 7)>(ru, rv, lane);     // descend strides S/4..32 -> m = S/128..1
}

__global__ __launch_bounds__(THREADS, 4) void w1_rows_kernel(
    const float* __restrict__ pred,
    const float* __restrict__ tru,
    float* __restrict__ out,
    float scale)
{
    // Staging for UPPER threads only (t&64): 128 slots x stride 33 = 16896 B.
    __shared__ float xbuf[128 * 33];
    __shared__ float wsum[THREADS / 64];

    const int tid  = threadIdx.x;
    const int t    = tid & 127;            // thread index within the row (0..127)
    const int lane = tid & 63;
    const int row  = blockIdx.x * 2 + (tid >> 7);
    const size_t base = (size_t)row * N_ELEM + (size_t)t * V;

    // Blocked layout: row-thread t owns global indices [32t, 32t+32).
    float ru[V], rv[V];
    {
        const float4* u4 = (const float4*)(pred + base);
        const float4* v4 = (const float4*)(tru  + base);
        #pragma unroll
        for (int c = 0; c < V / 4; ++c) {
            float4 a = u4[c], b = v4[c];
            ru[4*c+0] = a.x; ru[4*c+1] = a.y; ru[4*c+2] = a.z; ru[4*c+3] = a.w;
            rv[4*c+0] = b.x; rv[4*c+1] = b.y; rv[4*c+2] = b.z; rv[4*c+3] = b.w;
        }
    }

    // Stages S=2..32: fully in-register ascending sort of each 32-run.
    reg_merge<2>(ru);  reg_merge<2>(rv);
    reg_merge<4>(ru);  reg_merge<4>(rv);
    reg_merge<8>(ru);  reg_merge<8>(rv);
    reg_merge<16>(ru); reg_merge<16>(rv);
    reg_merge<32>(ru); reg_merge<32>(rv);

    // Stages S=64..2048: cross-lane mirror + descend, everything ascending.
    stage_m<64>(ru, rv, lane);
    stage_m<128>(ru, rv, lane);
    stage_m<256>(ru, rv, lane);
    stage_m<512>(ru, rv, lane);
    stage_m<1024>(ru, rv, lane);
    stage_m<2048>(ru, rv, lane);

    // Stage S=4096: mirror pass g <-> g^4095, i.e. (t,k) <-> (t^127, 31-k).
    // Wave-role split: uppers (t&64) stage all 32 regs; lowers read partner
    // reversed, keep min, write max back; uppers re-read. Wave-uniform branches.
    {
        const bool is_upper = (t & 64) != 0;
        const int  slot_row = (tid >> 7) * 64;
        const int  my_base  = (slot_row + lane) * 33;        // uppers' own slot
        const int  pa_base  = (slot_row + (63 - lane)) * 33; // lowers' partner slot

        // ---- array u ----
        if (is_upper) {
            #pragma unroll
            for (int k = 0; k < V; ++k) xbuf[my_base + k] = ru[k];
        }
        __syncthreads();
        if (!is_upper) {
            #pragma unroll
            for (int k = 0; k < V; ++k) {
                const int  e = V - 1 - k;
                const float o  = xbuf[pa_base + e];
                const float mx = fmaxf(ru[k], o);
                ru[k] = fminf(ru[k], o);          // lower keeps min
                xbuf[pa_base + e] = mx;           // partner's result
            }
        }
        __syncthreads();
        if (is_upper) {
            #pragma unroll
            for (int k = 0; k < V; ++k) ru[k] = xbuf[my_base + k];
        }

        // ---- array v ---- (uppers' own-slot read->write is program-ordered)
        if (is_upper) {
            #pragma unroll
            for (int k = 0; k < V; ++k) xbuf[my_base + k] = rv[k];
        }
        __syncthreads();
        if (!is_upper) {
            #pragma unroll
            for (int k = 0; k < V; ++k) {
                const int  e = V - 1 - k;
                const float o  = xbuf[pa_base + e];
                const float mx = fmaxf(rv[k], o);
                rv[k] = fminf(rv[k], o);
                xbuf[pa_base + e] = mx;
            }
        }
        __syncthreads();
        if (is_upper) {
            #pragma unroll
            for (int k = 0; k < V; ++k) rv[k] = xbuf[my_base + k];
        }

        cross_descend<32>(ru, rv, lane);       // strides 1024..32 then reg tail
    }

    // Epilogue: per-thread |diff| sum, wave reduce, block reduce, one atomic.
    float part = 0.f;
    #pragma unroll
    for (int k = 0; k < V; ++k) part += fabsf(ru[k] - rv[k]);

    #pragma unroll
    for (int off = 32; off > 0; off >>= 1)
        part += __shfl_down(part, off, 64);

    const int wid = tid >> 6;
    if (lane == 0) wsum[wid] = part;
    __syncthreads();
    if (tid == 0) {
        float tot = wsum[0] + wsum[1] + wsum[2] + wsum[3];
        atomicAdd(out, tot * scale);
    }
}

extern "C" void kernel_launch(void* const* d_in, const int* in_sizes, int n_in,
                              void* d_out, int out_size, void* d_ws, size_t ws_size,
                              hipStream_t stream)
{
    (void)n_in; (void)out_size; (void)d_ws; (void)ws_size;

    const float* pred = (const float*)d_in[0];
    const float* tru  = (const float*)d_in[1];
    float* out = (float*)d_out;

    const int B = in_sizes[0] / N_ELEM;   // 4096 rows

    hipMemsetAsync(out, 0, sizeof(float), stream);

    const float scale = 1.0f / ((float)N_ELEM * (float)B);
    w1_rows_kernel<<<B / 2, THREADS, 0, stream>>>(pred, tru, out, scale);
}